// Round 19
// baseline (54.177 us; speedup 1.0000x reference)
//
#include <hip/hip_runtime.h>
#include <hip/hip_bf16.h>
#include <math.h>

#define B_N   256
#define EMB_N 512
#define CLS_N 20000
#define NMB   157          // class tiles of 128 (157*128 = 20096)
#define PI_F  3.14159265f
#define F_CONST ((float)(1.1 / 1501.1))

typedef __bf16 bf16x8 __attribute__((ext_vector_type(8)));
typedef float  f32x4  __attribute__((ext_vector_type(4)));
typedef unsigned short u16x4 __attribute__((ext_vector_type(4)));

__device__ __forceinline__ unsigned short f2bf(float f) {
    unsigned u = __float_as_uint(f);
    unsigned r = (u + 0x7FFFu + ((u >> 16) & 1u)) >> 16;  // RNE
    return (unsigned short)r;
}

__device__ __forceinline__ void merge4(float& M, float& S, float& VM, int& VI,
                                       float m2, float s2, float vm2, int vi2) {
    float mn = fmaxf(M, m2);
    if (mn == -INFINITY) { S = 0.f; }
    else S = S * __expf(M - mn) + s2 * __expf(m2 - mn);
    M = mn;
    if (vm2 > VM || (vm2 == VM && vi2 < VI)) { VM = vm2; VI = vi2; }
}

// ---------------- prep: per-row scalars + bf16 stacked batch operand ----------------
__global__ __launch_bounds__(256) void prep_kernel(
    const float* __restrict__ emb, const int* __restrict__ y,
    const float* __restrict__ W,
    unsigned short* __restrict__ Abf,
    float* __restrict__ xlen_a, float* __restrict__ inv_xlen_a,
    float* __restrict__ inv_wny_a, float* __restrict__ mod_val_a,
    float* __restrict__ accums)
{
    const int b = blockIdx.x;
    const int t = threadIdx.x;
    if (b == 0 && t < 4) accums[t] = 0.f;   // ce, acc, inter, counter
    const int yb = y[b];
    const float* erow = emb + (size_t)b * EMB_N;
    float se = 0.f, sw = 0.f, dt = 0.f;
    for (int e = t; e < EMB_N; e += 256) {
        float ev = erow[e];
        float wv = W[(size_t)e * CLS_N + yb];
        Abf[(size_t)b * EMB_N + e]         = f2bf(ev);
        Abf[(size_t)(B_N + b) * EMB_N + e] = f2bf(wv);
        se += ev * ev; sw += wv * wv; dt += ev * wv;
    }
    __shared__ float r0[256], r1[256], r2[256];
    r0[t] = se; r1[t] = sw; r2[t] = dt;
    __syncthreads();
    for (int s = 128; s > 0; s >>= 1) {
        if (t < s) { r0[t] += r0[t + s]; r1[t] += r1[t + s]; r2[t] += r2[t + s]; }
        __syncthreads();
    }
    if (t == 0) {
        float xlen = sqrtf(r0[0]);
        float wn   = sqrtf(r1[0]);
        float inv_x = 1.f / xlen;
        float inv_w = 1.f / wn;
        float cos_t = r2[0] * inv_w * inv_x;
        cos_t = fminf(1.f, fmaxf(-1.f, cos_t));
        float c2 = cos_t * cos_t;
        float cos_m = 8.f * c2 * c2 - 8.f * c2 + 1.f;
        float theta = acosf(cos_t);
        float k = floorf(4.f * theta / PI_F);
        float sgn = 1.f - 2.f * fmodf(k, 2.f);
        float phi = sgn * cos_m - 2.f * k;
        float cos_s = cos_t * xlen;
        float phi_s = phi * xlen;
        xlen_a[b] = xlen;
        inv_xlen_a[b] = inv_x;
        inv_wny_a[b] = inv_w;
        mod_val_a[b] = cos_s + F_CONST * (phi_s - cos_s);
    }
}

// ---------------- fused MFMA GEMM: 512 threads / 8 waves per block ----------------
// Tile 128 classes x 128 batch; 628 blocks (m204 XCD map) -> ~19.6 waves/CU, fully
// co-resident. Wave = 64c x 32b (acc[4][2]). A: W fp32 -> reg (1 step ahead) -> bf16
// LDS (80B rows, dbuf). B: global_load_lds (1/wave) into 4 slabs. BK=32, 16 steps,
// single fenced barrier/step + setprio; counted vmcnt(5).
__global__ __launch_bounds__(512, 4) void mfma_gemm_kernel(
    const float* __restrict__ W, const unsigned short* __restrict__ Abf,
    const int* __restrict__ y,
    const float* __restrict__ xlen_a, const float* __restrict__ inv_xlen_a,
    const float* __restrict__ inv_wny_a,
    float* __restrict__ logits, float4* __restrict__ partials,
    float* __restrict__ inter_sum)
{
    __shared__ alignas(16) char smem[53248];   // sA dbuf 2x10240 | sB slabs 4x8192
    // epilogue overlays (staging dead after loop)
    float*  sSq   = (float*)smem;                 // [8][128] = 4 KB
    float*  sIwc  = (float*)(smem + 4096);        // 128 floats
    float4* sPart = (float4*)(smem + 4608);       // [128][2] = 4 KB
    float*  red   = (float*)(smem + 8704);        // 512 floats

    // m204 bijective XCD-chunked mapping: 628 = 4*79 + 4*78
    const int orig = blockIdx.x;
    const int xcd  = orig & 7;
    const int wgid = (xcd < 4 ? xcd * 79 : 316 + (xcd - 4) * 78) + (orig >> 3);
    const int tile  = wgid >> 2;
    const int slice = wgid & 3;          // 0,1: logits; 2,3: MHE
    const int m0    = tile * 128;
    const int gn0   = slice * 128;

    const int t    = threadIdx.x;
    const int lane = t & 63;
    const int wid  = t >> 6;             // 0..7
    const int wr   = wid >> 2;           // class half (64 rows)
    const int wq   = wid & 3;            // batch quarter (32 cols)
    const int r16  = lane & 15;
    const int kh   = lane >> 4;

    const char* Bb = (const char*)Abf;

    f32x4 acc[4][2] = {};
    float2 aq[2][4];
    float ssq0 = 0.f, ssq1 = 0.f;

    // A staging: thread = class pair (c2, c2+1), k-quad ko (4 k's per step)
    const int c2 = (t & 63) * 2;
    const int ko = t >> 6;               // 0..7
    const int gc = min(m0 + c2, CLS_N - 2);

    // B staging map (pre-swizzled source, linear LDS dest)
    const int srow = lane >> 2;
    const int srcq = (lane & 3) ^ ((lane >> 2) & 3);

    #define ISSUE_A(kt, s)                                                        \
        { _Pragma("unroll")                                                       \
          for (int p = 0; p < 4; ++p)                                             \
              aq[s][p] = *reinterpret_cast<const float2*>(                        \
                  &W[(size_t)((kt) + ko * 4 + p) * CLS_N + gc]);                  \
        }

    #define ISSUE_B(kt, slab)                                                     \
        { int row = wid * 16 + srow;                                              \
          __builtin_amdgcn_global_load_lds(                                       \
              (const __attribute__((address_space(1))) unsigned int*)             \
                  (Bb + (size_t)(gn0 + row) * 1024 + (size_t)(kt) * 2             \
                      + srcq * 16),                                               \
              (__attribute__((address_space(3))) unsigned int*)                   \
                  (smem + 20480 + (slab) * 8192 + wid * 1024),                    \
              16, 0, 0); }

    #define WRITE_A(s, buf)                                                       \
        { u16x4 u0, u1; float s0 = 0.f, s1 = 0.f;                                 \
          _Pragma("unroll")                                                       \
          for (int p = 0; p < 4; ++p) {                                           \
              float vx = aq[s][p].x, vy = aq[s][p].y;                             \
              u0[p] = f2bf(vx); u1[p] = f2bf(vy);                                 \
              s0 += vx * vx; s1 += vy * vy;                                       \
          }                                                                       \
          ssq0 += s0; ssq1 += s1;                                                 \
          *reinterpret_cast<u16x4*>(smem + (buf) * 10240 + c2 * 80 + ko * 8) = u0; \
          *reinterpret_cast<u16x4*>(smem + (buf) * 10240 + (c2 + 1) * 80 + ko * 8) = u1; }

    #define COMPUTE(buf, slab)                                                    \
        { bf16x8 af[4], bfr[2];                                                   \
          _Pragma("unroll")                                                       \
          for (int mi = 0; mi < 4; ++mi) {                                        \
              int row = wr * 64 + mi * 16 + r16;                                  \
              af[mi] = *reinterpret_cast<const bf16x8*>(                          \
                  smem + (buf) * 10240 + row * 80 + kh * 16);                     \
          }                                                                       \
          _Pragma("unroll")                                                       \
          for (int ni = 0; ni < 2; ++ni) {                                        \
              int rowb = wq * 32 + ni * 16 + r16;                                 \
              bfr[ni] = *reinterpret_cast<const bf16x8*>(                         \
                  smem + 20480 + (slab) * 8192 + rowb * 64                        \
                  + ((kh ^ (rowb & 3)) << 4));                                    \
          }                                                                       \
          __builtin_amdgcn_s_setprio(1);                                          \
          _Pragma("unroll")                                                       \
          for (int mi = 0; mi < 4; ++mi)                                          \
              _Pragma("unroll")                                                   \
              for (int ni = 0; ni < 2; ++ni)                                      \
                  acc[mi][ni] = __builtin_amdgcn_mfma_f32_16x16x32_bf16(          \
                      af[mi], bfr[ni], acc[mi][ni], 0, 0, 0);                     \
          __builtin_amdgcn_s_setprio(0); }

    #define FENCE() __builtin_amdgcn_sched_barrier(0);

    ISSUE_A(0, 0)  ISSUE_B(0, 0)

    #pragma unroll
    for (int tt = 0; tt < 16; ++tt) {
        WRITE_A(tt & 1, tt & 1)          // implicit wait covers only aq[tt&1]
        if (tt < 15) {
            ISSUE_A((tt + 1) * 32, (tt + 1) & 1)
            ISSUE_B((tt + 1) * 32, (tt + 1) & 3)
            FENCE()
            // outstanding: B(tt)1 A(tt+1)4 B(tt+1)1 = 6 -> retire B(tt) only
            asm volatile("s_waitcnt vmcnt(5) lgkmcnt(0)" ::: "memory");
        } else {
            FENCE()
            asm volatile("s_waitcnt vmcnt(0) lgkmcnt(0)" ::: "memory");
        }
        FENCE()
        asm volatile("s_barrier" ::: "memory");
        FENCE()
        COMPUTE(tt & 1, tt & 3)
        FENCE()
        // no second barrier: A-dbuf + B-4slab tolerate 1-step wave drift
    }
    #undef ISSUE_A
    #undef ISSUE_B
    #undef WRITE_A
    #undef COMPUTE
    #undef FENCE

    __syncthreads();   // drain; smem becomes epilogue overlay

    // ---- per-class inverse norms (8 k-quad partials per class) ----
    sSq[ko * 128 + c2]     = ssq0;
    sSq[ko * 128 + c2 + 1] = ssq1;
    __syncthreads();
    if (t < 128) {
        float s = 0.f;
        #pragma unroll
        for (int g = 0; g < 8; ++g) s += sSq[g * 128 + t];
        sIwc[t] = rsqrtf(s);
    }
    __syncthreads();

    float iwc[4][4];
    #pragma unroll
    for (int mi = 0; mi < 4; ++mi)
        #pragma unroll
        for (int r = 0; r < 4; ++r)
            iwc[mi][r] = sIwc[wr * 64 + mi * 16 + kh * 4 + r];

    if (slice < 2) {
        // ---- logits + fused per-thread softmax/argmax ----
        #pragma unroll
        for (int ni = 0; ni < 2; ++ni) {
            int bl = wq * 32 + ni * 16 + r16;   // 0..127
            int b  = gn0 + bl;                   // 0..255
            float xl  = xlen_a[b];
            float ixl = inv_xlen_a[b];
            float M = -INFINITY, S = 0.f, VM = -INFINITY; int VI = 0x7fffffff;
            #pragma unroll
            for (int mi = 0; mi < 4; ++mi) {
                int cb = m0 + wr * 64 + mi * 16 + kh * 4;
                if (cb < CLS_N) {            // quad-aligned boundary: fully valid
                    f32x4 vout;
                    #pragma unroll
                    for (int r = 0; r < 4; ++r) {
                        float cosv = acc[mi][ni][r] * iwc[mi][r] * ixl;
                        cosv = fminf(1.f, fmaxf(-1.f, cosv));
                        float v = cosv * xl;
                        vout[r] = v;
                        if (v > M) { S = S * __expf(M - v) + 1.f; M = v; }
                        else       { S += __expf(v - M); }
                        if (v > VM) { VM = v; VI = cb + r; }
                    }
                    *reinterpret_cast<f32x4*>(&logits[(size_t)b * CLS_N + cb]) = vout;
                }
            }
            // merge across kh groups (lanes l, l^16, l^32, l^48)
            #pragma unroll
            for (int d = 16; d < 64; d <<= 1) {
                float m2  = __shfl_xor(M, d);
                float s2  = __shfl_xor(S, d);
                float vm2 = __shfl_xor(VM, d);
                int   vi2 = __shfl_xor(VI, d);
                merge4(M, S, VM, VI, m2, s2, vm2, vi2);
            }
            if (kh == 0) sPart[bl * 2 + wr] = make_float4(M, S, VM, __int_as_float(VI));
        }
        __syncthreads();
        if (t < 128) {
            float4 p0 = sPart[t * 2 + 0], p1 = sPart[t * 2 + 1];
            float M = p0.x, S = p0.y, VM = p0.z; int VI = __float_as_int(p0.w);
            merge4(M, S, VM, VI, p1.x, p1.y, p1.z, __float_as_int(p1.w));
            partials[(size_t)(gn0 + t) * NMB + tile] =
                make_float4(M, S, VM, __int_as_float(VI));
        }
    } else {
        // ---- MHE inter-class term ----
        float part = 0.f;
        #pragma unroll
        for (int ni = 0; ni < 2; ++ni) {
            int b = (slice - 2) * 128 + wq * 32 + ni * 16 + r16;   // 0..255
            float iwy = inv_wny_a[b];
            int   yb  = y[b];
            #pragma unroll
            for (int mi = 0; mi < 4; ++mi) {
                int cb = m0 + wr * 64 + mi * 16 + kh * 4;
                #pragma unroll
                for (int r = 0; r < 4; ++r) {
                    int c = cb + r;
                    if (c < CLS_N && c != yb) {
                        float cww = acc[mi][ni][r] * iwc[mi][r] * iwy;
                        float d2 = fmaxf(2.f - 2.f * cww, 0.f);
                        part += 1.f / d2;
                    }
                }
            }
        }
        red[t] = part;
        __syncthreads();
        for (int s = 256; s > 0; s >>= 1) {
            if (t < s) red[t] += red[t + s];
            __syncthreads();
        }
        if (t == 0) atomicAdd(inter_sum, red[0]);
    }
}

// ---------------- reduce + finalize (last-block election) ----------------
__global__ __launch_bounds__(64) void reduce_kernel(
    const float4* __restrict__ partials, const float* __restrict__ logits,
    const int* __restrict__ y, const float* __restrict__ mod_val_a,
    float* __restrict__ accums, float* __restrict__ out)
{
    const int b = blockIdx.x;
    const int t = threadIdx.x;
    float M = -INFINITY, S = 0.f, VM = -INFINITY; int VI = 0x7fffffff;
    for (int i = t; i < NMB; i += 64) {
        float4 p = partials[(size_t)b * NMB + i];
        merge4(M, S, VM, VI, p.x, p.y, p.z, __float_as_int(p.w));
    }
    #pragma unroll
    for (int d = 1; d < 64; d <<= 1) {
        float m2  = __shfl_xor(M, d);
        float s2  = __shfl_xor(S, d);
        float vm2 = __shfl_xor(VM, d);
        int   vi2 = __shfl_xor(VI, d);
        merge4(M, S, VM, VI, m2, s2, vm2, vi2);
    }
    if (t == 0) {
        int   yb  = y[b];
        float vyb = logits[(size_t)b * CLS_N + yb];
        float mv  = mod_val_a[b];
        float m2 = fmaxf(M, mv);
        float s2 = S * __expf(M - m2) - __expf(vyb - m2) + __expf(mv - m2);
        float lse = m2 + logf(s2);
        atomicAdd(&accums[0], -(mv - lse));
        if (VI == yb) atomicAdd(&accums[1], 1.f);
        __threadfence();
        int old = atomicAdd((int*)&accums[3], 1);
        if (old == B_N - 1) {
            float ce    = atomicAdd(&accums[0], 0.f) / (float)B_N;
            float acc   = atomicAdd(&accums[1], 0.f) / (float)B_N;
            float inter = atomicAdd(&accums[2], 0.f) / (float)((double)B_N * (CLS_N - 1));
            out[0] = ce + 0.01f * inter;
            out[(size_t)1 + (size_t)B_N * CLS_N + 0] = acc;
            out[(size_t)1 + (size_t)B_N * CLS_N + 1] = inter;
        }
    }
}

extern "C" void kernel_launch(void* const* d_in, const int* in_sizes, int n_in,
                              void* d_out, int out_size, void* d_ws, size_t ws_size,
                              hipStream_t stream) {
    const float* emb = (const float*)d_in[0];
    const int*   y   = (const int*)d_in[1];
    const float* W   = (const float*)d_in[2];
    float* out = (float*)d_out;
    float* logits = out + 1;   // [loss, logits(256x20000), acc, inter]

    // ws layout (bytes)
    const size_t ABF_OFF  = 0;                                  // 512*512*2 = 524288
    const size_t PART_OFF = 524288;                             // 256*157*16
    const size_t SC_OFF   = PART_OFF + (size_t)B_N * NMB * 16;

    unsigned short* Abf = (unsigned short*)((char*)d_ws + ABF_OFF);
    float4* partials   = (float4*)((char*)d_ws + PART_OFF);
    float*  xlen_a     = (float*)((char*)d_ws + SC_OFF);
    float*  inv_xlen_a = xlen_a + 256;
    float*  inv_wny_a  = xlen_a + 512;
    float*  mod_val_a  = xlen_a + 768;
    float*  accums     = xlen_a + 1024;   // ce, acc, inter, counter

    prep_kernel<<<B_N, 256, 0, stream>>>(emb, y, W, Abf,
                                         xlen_a, inv_xlen_a, inv_wny_a, mod_val_a,
                                         accums);
    mfma_gemm_kernel<<<628, 512, 0, stream>>>(W, Abf, y,
                                              xlen_a, inv_xlen_a, inv_wny_a,
                                              logits, partials, accums + 2);
    reduce_kernel<<<B_N, 64, 0, stream>>>(partials, logits, y, mod_val_a,
                                          accums, out);
}